// Round 7
// baseline (188.885 us; speedup 1.0000x reference)
//
#include <hip/hip_runtime.h>
#include <math.h>

#define MASK_THR 0.53f
#define BT 32
#define BPB 1024        // bins per bucket (LDS array size)
#define CAPN 4096       // slots per bucket (mean ~2164, sigma ~47 -> 40+ sigma)
#define CNTSTRIDE 16    // counters spread 64B apart

typedef unsigned long long u64;

// ---- Phase A: append candidates into per-bucket arrays. ----
// p in [0.53,1) => exponent fixed 126 => 23 mantissa bits order as p.
// Output needs only winner's instance n => val = (mant<<9)|(NB1-n):
// max val = max p, tie -> min n. val is never 0 (mant >= 0x3D70A).
__global__ __launch_bounds__(256) void k_binA(
        const float* __restrict__ prob, const int* __restrict__ coords,
        unsigned* __restrict__ cnt, u64* __restrict__ buf,
        int NE, int HW4, int NB1, const int* __restrict__ d_size1) {
    int i4 = blockIdx.x * blockDim.x + threadIdx.x;
    if (i4 * 4 >= NE) return;
    int size1 = *d_size1;
    float4 p = ((const float4*)prob)[i4];
    int4 x = ((const int4*)coords)[i4];
    int4 y = ((const int4*)(coords + NE))[i4];
    unsigned n = (unsigned)i4 / (unsigned)HW4;   // HW%4==0: 4 pixels share n
    unsigned tie = (unsigned)(NB1 - (int)n);
    float pv[4] = {p.x, p.y, p.z, p.w};
    int   xv[4] = {x.x, x.y, x.z, x.w};
    int   yv[4] = {y.x, y.y, y.z, y.w};
#pragma unroll
    for (int e = 0; e < 4; ++e) {
        if (pv[e] >= MASK_THR) {
            unsigned key = (unsigned)(xv[e] * size1 + yv[e]);
            unsigned b = key >> 10;
            unsigned v = ((__float_as_uint(pv[e]) & 0x7FFFFFu) << 9) | tie;
            unsigned pos = atomicAdd(&cnt[b * CNTSTRIDE], 1u);
            if (pos < CAPN)
                buf[(size_t)b * CAPN + pos] = ((u64)(key & (BPB - 1)) << 32) | v;
        }
    }
}

// ---- Phase B + finalize: block b merges bucket b via LDS atomicMax, then
// writes output segment [b*BPB, b*BPB+BPB) through rmap. ----
__global__ __launch_bounds__(256) void k_binBfin(
        const unsigned* __restrict__ cnt, const u64* __restrict__ buf,
        const float* __restrict__ rmap, float* __restrict__ out,
        int total, int NB1) {
    __shared__ unsigned bins[BPB];
    int b = blockIdx.x, tid = threadIdx.x;
    for (int i = tid; i < BPB; i += 256) bins[i] = 0u;
    __syncthreads();
    unsigned nIt = cnt[b * CNTSTRIDE];
    if (nIt > CAPN) nIt = CAPN;
    const u64* src = buf + (size_t)b * CAPN;
    for (unsigned i = tid; i < nIt; i += 256) {
        u64 kv = src[i];
        atomicMax(&bins[(unsigned)(kv >> 32)], (unsigned)kv);
    }
    __syncthreads();
    int base = b << 10;
    for (int i = tid; i < BPB; i += 256) {
        int g = base + i;
        if (g < total) {
            unsigned v = bins[i];
            out[g] = v ? rmap[NB1 - (int)(v & 0x1FFu)] : 0.0f;
        }
    }
}

// ---- Legacy direct-atomic scatter + finalize (fallback if ws too small) ----
__global__ __launch_bounds__(256) void k_scatter(
        const float* __restrict__ prob, const int* __restrict__ coords,
        unsigned* __restrict__ packed, int NE, int HW4, int NB1,
        const int* __restrict__ d_size1) {
    int i4 = blockIdx.x * blockDim.x + threadIdx.x;
    if (i4 * 4 >= NE) return;
    int size1 = *d_size1;
    float4 p = ((const float4*)prob)[i4];
    int4 x = ((const int4*)coords)[i4];
    int4 y = ((const int4*)(coords + NE))[i4];
    unsigned n = (unsigned)i4 / (unsigned)HW4;
    unsigned tie = (unsigned)(NB1 - (int)n);
    float pv[4] = {p.x, p.y, p.z, p.w};
    int   xv[4] = {x.x, x.y, x.z, x.w};
    int   yv[4] = {y.x, y.y, y.z, y.w};
#pragma unroll
    for (int e = 0; e < 4; ++e)
        if (pv[e] >= MASK_THR) {
            unsigned v = ((__float_as_uint(pv[e]) & 0x7FFFFFu) << 9) | tie;
            atomicMax(&packed[xv[e] * size1 + yv[e]], v);
        }
}

__global__ void k_finalize(const unsigned* __restrict__ packed,
                           const float* __restrict__ rmap,
                           float* __restrict__ out, int total, int NB1) {
    int i4 = blockIdx.x * blockDim.x + threadIdx.x;
    if (i4 * 4 >= total) return;
    uint4 u = ((const uint4*)packed)[i4];
    unsigned v[4] = {u.x, u.y, u.z, u.w};
    float o[4];
#pragma unroll
    for (int e = 0; e < 4; ++e)
        o[e] = v[e] ? rmap[NB1 - (int)(v[e] & 0x1FFu)] : 0.0f;
    ((float4*)out)[i4] = make_float4(o[0], o[1], o[2], o[3]);
}

// ---- matmul: 32x32 tile, 2x2/thread, split-K (blockIdx/nTiles = K-slab),
// inputs = elementwise sum of up to 4 partial buffers (exact: integer fp32),
// optional +I on both operands. >1 classification exact in fp32. ----
__global__ __launch_bounds__(256) void k_mm(
        const float* __restrict__ A0, const float* __restrict__ A1,
        const float* __restrict__ A2, const float* __restrict__ A3,
        const float* __restrict__ B0, const float* __restrict__ B1,
        const float* __restrict__ B2, const float* __restrict__ B3,
        float* __restrict__ C0, float* __restrict__ C1,
        float* __restrict__ C2, float* __restrict__ C3,
        int N, int addI, int kLen) {
    __shared__ float As[BT][BT + 1];
    __shared__ float Bs[BT][BT + 1];
    int NT = N / BT;
    int nTiles = NT * NT;
    int bid = blockIdx.x % nTiles;
    int sp  = blockIdx.x / nTiles;
    int kBase = sp * kLen;
    float* C = sp == 0 ? C0 : sp == 1 ? C1 : sp == 2 ? C2 : C3;
    int tid = threadIdx.x;
    int bx = bid % NT, by = bid / NT;
    int rowBase = by * BT, colBase = bx * BT;
    int tx = tid & 15, ty = tid >> 4;
    int lr = tid >> 3;
    int lc = (tid & 7) * 4;
    float a00 = 0, a01 = 0, a10 = 0, a11 = 0;
    for (int t = kBase; t < kBase + kLen; t += BT) {
        size_t ai = (size_t)(rowBase + lr) * N + t + lc;
        size_t bi = (size_t)(t + lr) * N + colBase + lc;
        float4 av = *(const float4*)(A0 + ai);
        float4 bv = *(const float4*)(B0 + bi);
        if (A1) { float4 w = *(const float4*)(A1 + ai);
                  av.x += w.x; av.y += w.y; av.z += w.z; av.w += w.w; }
        if (A2) { float4 w = *(const float4*)(A2 + ai);
                  av.x += w.x; av.y += w.y; av.z += w.z; av.w += w.w; }
        if (A3) { float4 w = *(const float4*)(A3 + ai);
                  av.x += w.x; av.y += w.y; av.z += w.z; av.w += w.w; }
        if (B1) { float4 w = *(const float4*)(B1 + bi);
                  bv.x += w.x; bv.y += w.y; bv.z += w.z; bv.w += w.w; }
        if (B2) { float4 w = *(const float4*)(B2 + bi);
                  bv.x += w.x; bv.y += w.y; bv.z += w.z; bv.w += w.w; }
        if (B3) { float4 w = *(const float4*)(B3 + bi);
                  bv.x += w.x; bv.y += w.y; bv.z += w.z; bv.w += w.w; }
        if (addI) {
            int r = rowBase + lr, c = t + lc;
            if (r == c + 0) av.x += 1.0f;
            if (r == c + 1) av.y += 1.0f;
            if (r == c + 2) av.z += 1.0f;
            if (r == c + 3) av.w += 1.0f;
            int r2 = t + lr, c2 = colBase + lc;
            if (r2 == c2 + 0) bv.x += 1.0f;
            if (r2 == c2 + 1) bv.y += 1.0f;
            if (r2 == c2 + 2) bv.z += 1.0f;
            if (r2 == c2 + 3) bv.w += 1.0f;
        }
        As[lr][lc + 0] = av.x; As[lr][lc + 1] = av.y;
        As[lr][lc + 2] = av.z; As[lr][lc + 3] = av.w;
        Bs[lr][lc + 0] = bv.x; Bs[lr][lc + 1] = bv.y;
        Bs[lr][lc + 2] = bv.z; Bs[lr][lc + 3] = bv.w;
        __syncthreads();
#pragma unroll
        for (int k = 0; k < BT; ++k) {
            float a0 = As[ty * 2][k], a1 = As[ty * 2 + 1][k];
            float b0 = Bs[k][tx * 2], b1 = Bs[k][tx * 2 + 1];
            a00 += a0 * b0; a01 += a0 * b1;
            a10 += a1 * b0; a11 += a1 * b1;
        }
        __syncthreads();
    }
    int r0 = rowBase + ty * 2, c0 = colBase + tx * 2;
    C[(size_t)r0 * N + c0] = a00;
    C[(size_t)r0 * N + c0 + 1] = a01;
    C[(size_t)(r0 + 1) * N + c0] = a10;
    C[(size_t)(r0 + 1) * N + c0 + 1] = a11;
}

// remap[j] = 1 + max({j} U {i != j : M10[i][j] > 1}); classification symmetric
// (symmetric adjacency => symmetric counts; test exact in fp32) => read ROW j.
__global__ void k_remap(const float* __restrict__ R0, const float* __restrict__ R1,
                        const float* __restrict__ R2, const float* __restrict__ R3,
                        float* __restrict__ rmap, int N) {
    int j = blockIdx.x;
    int lane = threadIdx.x;  // 64
    size_t o = (size_t)j * N;
    int best = j;
    for (int i = lane; i < N; i += 64) {
        float v = R0[o + i];
        if (R1) v += R1[o + i];
        if (R2) v += R2[o + i];
        if (R3) v += R3[o + i];
        if (i != j && v > 1.0f && i > best) best = i;
    }
    for (int off = 32; off; off >>= 1) {
        int o2 = __shfl_down(best, off);
        if (o2 > best) best = o2;
    }
    if (lane == 0) rmap[j] = (float)(best + 1);
}

extern "C" void kernel_launch(void* const* d_in, const int* in_sizes, int n_in,
                              void* d_out, int out_size, void* d_ws, size_t ws_size,
                              hipStream_t stream) {
    const float* prob   = (const float*)d_in[0];
    const int*   coords = (const int*)d_in[1];
    const float* adj    = (const float*)d_in[2];
    const int*   dsz1   = (const int*)d_in[4];

    const int NE = in_sizes[0];            // N*h*w = 4718592
    const int NN = in_sizes[2];            // N*N
    int N = (int)(sqrt((double)NN) + 0.5); // 512
    const int HW = NE / N;                 // 9216
    const int total = out_size;            // 1048576
    const int NB1 = N - 1;
    const size_t bufB = (size_t)NN * 4;    // 1 MB
    const int NBUCK = (total + BPB - 1) / BPB;   // 1024

    const size_t cntB = (size_t)NBUCK * CNTSTRIDE * 4;       // 64 KB
    const size_t binB = (size_t)NBUCK * CAPN * 8;            // 32 MB
    const size_t newNeed = cntB + binB + bufB * 16 + 4096;
    char* ws = (char*)d_ws;

    if (ws_size >= newNeed) {
        // ---- binned path, split-K=4 ----
        unsigned* cnt = (unsigned*)ws;
        u64* buf = (u64*)(ws + cntB);
        size_t off = cntB + binB;
        float* m[16];
        for (int i = 0; i < 16; ++i) { m[i] = (float*)(ws + off); off += bufB; }
        float* rmap = (float*)(ws + off);
        // q=m[0..3]:M^2  r=m[4..7]:M^4  s=m[8..11]:M^8  t=m[12..15]:M^10

        hipMemsetAsync(cnt, 0, cntB, stream);

        k_binA<<<(NE / 4 + 255) / 256, 256, 0, stream>>>(
            prob, coords, cnt, buf, NE, HW / 4, NB1, dsz1);

        const int nTiles = (N / BT) * (N / BT);
        const int kLen = N / 4;
        dim3 mg(nTiles * 4);
        float* Z = nullptr;
        k_mm<<<mg, 256, 0, stream>>>(adj, Z, Z, Z, adj, Z, Z, Z,
                                     m[0], m[1], m[2], m[3], N, 1, kLen);
        k_mm<<<mg, 256, 0, stream>>>(m[0], m[1], m[2], m[3],
                                     m[0], m[1], m[2], m[3],
                                     m[4], m[5], m[6], m[7], N, 0, kLen);
        k_mm<<<mg, 256, 0, stream>>>(m[4], m[5], m[6], m[7],
                                     m[4], m[5], m[6], m[7],
                                     m[8], m[9], m[10], m[11], N, 0, kLen);
        k_mm<<<mg, 256, 0, stream>>>(m[8], m[9], m[10], m[11],
                                     m[0], m[1], m[2], m[3],
                                     m[12], m[13], m[14], m[15], N, 0, kLen);
        k_remap<<<N, 64, 0, stream>>>(m[12], m[13], m[14], m[15], rmap, N);

        k_binBfin<<<NBUCK, 256, 0, stream>>>(cnt, buf, rmap,
                                             (float*)d_out, total, NB1);
    } else {
        // ---- fallback: direct atomics, split-K=2 ----
        unsigned* packed = (unsigned*)ws;
        size_t off = (size_t)total * 4;
        float* m[8];
        for (int i = 0; i < 8; ++i) { m[i] = (float*)(ws + off); off += bufB; }
        float* rmap = (float*)(ws + off);

        hipMemsetAsync(packed, 0, (size_t)total * 4, stream);
        k_scatter<<<(NE / 4 + 255) / 256, 256, 0, stream>>>(
            prob, coords, packed, NE, HW / 4, NB1, dsz1);

        const int nTiles = (N / BT) * (N / BT);
        const int kLen = N / 2;
        dim3 mg(nTiles * 2);
        float* Z = nullptr;
        k_mm<<<mg, 256, 0, stream>>>(adj, Z, Z, Z, adj, Z, Z, Z,
                                     m[0], m[1], Z, Z, N, 1, kLen);
        k_mm<<<mg, 256, 0, stream>>>(m[0], m[1], Z, Z, m[0], m[1], Z, Z,
                                     m[2], m[3], Z, Z, N, 0, kLen);
        k_mm<<<mg, 256, 0, stream>>>(m[2], m[3], Z, Z, m[2], m[3], Z, Z,
                                     m[4], m[5], Z, Z, N, 0, kLen);
        k_mm<<<mg, 256, 0, stream>>>(m[4], m[5], Z, Z, m[0], m[1], Z, Z,
                                     m[6], m[7], Z, Z, N, 0, kLen);
        k_remap<<<N, 64, 0, stream>>>(m[6], m[7], Z, Z, rmap, N);
        k_finalize<<<(total / 4 + 255) / 256, 256, 0, stream>>>(
            packed, rmap, (float*)d_out, total, NB1);
    }
}

// Round 8
// 155.545 us; speedup vs baseline: 1.2143x; 1.2143x over previous
//
#include <hip/hip_runtime.h>
#include <math.h>

#define MASK_THR 0.53f
#define BPB 1024        // bins per bucket (LDS merge array)
#define CAPN 4096       // slots per bucket (mean ~2164, sd ~47 -> 40+ sigma)
#define CNTSTRIDE 16    // global counters spread 64B apart
#define NBLKA 512       // binA blocks

typedef unsigned long long u64;

// ---- Phase A v2: two-pass block-local binning. ----
// Pass 1: LDS histogram of bucket counts for this block's contiguous chunk.
// Reserve: ONE global atomicAdd per (block,bucket) claims a contiguous range.
// Pass 2: re-stream (L2-warm) and append into the reserved range (contiguous
// per (block,bucket) => shared-line writes, no per-candidate RMW).
// Packing: p in [0.53,1) => exponent fixed 126 => mantissa orders as p.
// Output needs only winner's instance n => val=(mant<<9)|(NB1-n):
// max val = max p, tie -> min n. val always nonzero.
__global__ __launch_bounds__(256) void k_binA(
        const float* __restrict__ prob, const int* __restrict__ coords,
        unsigned* __restrict__ gcnt, u64* __restrict__ buf,
        int NE, int HW4, int NB1, const int* __restrict__ d_size1,
        int i4PerBlk, int nbuck) {
    __shared__ unsigned hist[BPB];
    __shared__ unsigned rstart[BPB];
    int tid = threadIdx.x;
    for (int i = tid; i < nbuck; i += 256) hist[i] = 0u;
    __syncthreads();
    int size1 = *d_size1;
    int NE4 = NE >> 2;
    int i4Base = blockIdx.x * i4PerBlk;
    int i4End = min(i4Base + i4PerBlk, NE4);
    // pass 1: count
    for (int i4 = i4Base + tid; i4 < i4End; i4 += 256) {
        float4 p = ((const float4*)prob)[i4];
        int4 x = ((const int4*)coords)[i4];
        int4 y = ((const int4*)(coords + NE))[i4];
        float pv[4] = {p.x, p.y, p.z, p.w};
        int   xv[4] = {x.x, x.y, x.z, x.w};
        int   yv[4] = {y.x, y.y, y.z, y.w};
#pragma unroll
        for (int e = 0; e < 4; ++e)
            if (pv[e] >= MASK_THR) {
                unsigned key = (unsigned)(xv[e] * size1 + yv[e]);
                atomicAdd(&hist[key >> 10], 1u);
            }
    }
    __syncthreads();
    // reserve ranges; reset hist to use as running offsets
    for (int b = tid; b < nbuck; b += 256) {
        unsigned c = hist[b];
        rstart[b] = c ? atomicAdd(&gcnt[b * CNTSTRIDE], c) : 0u;
        hist[b] = 0u;
    }
    __syncthreads();
    // pass 2: append
    for (int i4 = i4Base + tid; i4 < i4End; i4 += 256) {
        float4 p = ((const float4*)prob)[i4];
        int4 x = ((const int4*)coords)[i4];
        int4 y = ((const int4*)(coords + NE))[i4];
        unsigned n = (unsigned)i4 / (unsigned)HW4;   // HW%4==0: 4 px share n
        unsigned tie = (unsigned)(NB1 - (int)n);
        float pv[4] = {p.x, p.y, p.z, p.w};
        int   xv[4] = {x.x, x.y, x.z, x.w};
        int   yv[4] = {y.x, y.y, y.z, y.w};
#pragma unroll
        for (int e = 0; e < 4; ++e)
            if (pv[e] >= MASK_THR) {
                unsigned key = (unsigned)(xv[e] * size1 + yv[e]);
                unsigned b = key >> 10;
                unsigned v = ((__float_as_uint(pv[e]) & 0x7FFFFFu) << 9) | tie;
                unsigned pos = rstart[b] + atomicAdd(&hist[b], 1u);
                if (pos < CAPN)
                    buf[(size_t)b * CAPN + pos] =
                        ((u64)(key & (BPB - 1)) << 32) | v;
            }
    }
}

// ---- Phase B + finalize: block b merges bucket b via LDS atomicMax, then
// writes output segment [b*BPB, (b+1)*BPB) through rmap. ----
__global__ __launch_bounds__(256) void k_binBfin(
        const unsigned* __restrict__ gcnt, const u64* __restrict__ buf,
        const float* __restrict__ rmap, float* __restrict__ out,
        int total, int NB1) {
    __shared__ unsigned bins[BPB];
    int b = blockIdx.x, tid = threadIdx.x;
    for (int i = tid; i < BPB; i += 256) bins[i] = 0u;
    __syncthreads();
    unsigned nIt = gcnt[b * CNTSTRIDE];
    if (nIt > CAPN) nIt = CAPN;
    const u64* src = buf + (size_t)b * CAPN;
    for (unsigned i = tid; i < nIt; i += 256) {
        u64 kv = src[i];
        atomicMax(&bins[(unsigned)(kv >> 32)], (unsigned)kv);
    }
    __syncthreads();
    int base = b << 10;
    for (int i = tid; i < BPB; i += 256) {
        int g = base + i;
        if (g < total) {
            unsigned v = bins[i];
            out[g] = v ? rmap[NB1 - (int)(v & 0x1FFu)] : 0.0f;
        }
    }
}

// ---- Fallback: direct-atomic scatter + finalize (proven, 90us) ----
__global__ __launch_bounds__(256) void k_scatter(
        const float* __restrict__ prob, const int* __restrict__ coords,
        unsigned* __restrict__ packed, int NE, int HW4, int NB1,
        const int* __restrict__ d_size1) {
    int i4 = blockIdx.x * blockDim.x + threadIdx.x;
    if (i4 * 4 >= NE) return;
    int size1 = *d_size1;
    float4 p = ((const float4*)prob)[i4];
    int4 x = ((const int4*)coords)[i4];
    int4 y = ((const int4*)(coords + NE))[i4];
    unsigned n = (unsigned)i4 / (unsigned)HW4;
    unsigned tie = (unsigned)(NB1 - (int)n);
    float pv[4] = {p.x, p.y, p.z, p.w};
    int   xv[4] = {x.x, x.y, x.z, x.w};
    int   yv[4] = {y.x, y.y, y.z, y.w};
#pragma unroll
    for (int e = 0; e < 4; ++e)
        if (pv[e] >= MASK_THR) {
            unsigned v = ((__float_as_uint(pv[e]) & 0x7FFFFFu) << 9) | tie;
            atomicMax(&packed[xv[e] * size1 + yv[e]], v);
        }
}

__global__ void k_finalize(const unsigned* __restrict__ packed,
                           const float* __restrict__ rmap,
                           float* __restrict__ out, int total, int NB1) {
    int i4 = blockIdx.x * blockDim.x + threadIdx.x;
    if (i4 * 4 >= total) return;
    uint4 u = ((const uint4*)packed)[i4];
    unsigned v[4] = {u.x, u.y, u.z, u.w};
    float o[4];
#pragma unroll
    for (int e = 0; e < 4; ++e)
        o[e] = v[e] ? rmap[NB1 - (int)(v[e] & 0x1FFu)] : 0.0f;
    ((float4*)out)[i4] = make_float4(o[0], o[1], o[2], o[3]);
}

// ---- matmul v2: 64x64 tile, 4x4 per thread, A transposed in LDS so both
// fragments load as ds_read_b128. Split-K=4 (blockIdx/nTiles = K-slab ->
// partial buffer). Inputs = elementwise sum of up to 4 partials (exact:
// integer-valued fp32 < 2^24). Optional +I on both operands. ----
#define BM 64
#define BK 32
#define LSTR 68   // LDS row stride (floats); 68*4B keeps float4 alignment
__global__ __launch_bounds__(256) void k_mm4(
        const float* __restrict__ A0, const float* __restrict__ A1,
        const float* __restrict__ A2, const float* __restrict__ A3,
        const float* __restrict__ B0, const float* __restrict__ B1,
        const float* __restrict__ B2, const float* __restrict__ B3,
        float* __restrict__ C0, float* __restrict__ C1,
        float* __restrict__ C2, float* __restrict__ C3,
        int N, int addI, int kLen) {
    __shared__ float As[BK][LSTR];   // As[k][m] = A[rowBase+m][t+k]
    __shared__ float Bs[BK][LSTR];   // Bs[k][n] = B[t+k][colBase+n]
    int NT = N / BM;                 // 8
    int nTiles = NT * NT;            // 64
    int bid = blockIdx.x % nTiles;
    int sp  = blockIdx.x / nTiles;
    int kBase = sp * kLen;
    float* C = sp == 0 ? C0 : sp == 1 ? C1 : sp == 2 ? C2 : C3;
    int tid = threadIdx.x;
    int bx = bid % NT, by = bid / NT;
    int rowBase = by * BM, colBase = bx * BM;
    int tx = tid & 15, ty = tid >> 4;     // 16x16 threads, 4x4 outputs each
    int lar = tid & 63;                   // A loader: row 0..63
    int lak = (tid >> 6) * 4;             // A loader: k base {0,4,8,12}
    int lbk = tid >> 4;                   // B loader: k 0..15
    int lbc = (tid & 15) * 4;             // B loader: col
    float acc[4][4] = {{0}};
    for (int t = kBase; t < kBase + kLen; t += BK) {
#pragma unroll
        for (int h = 0; h < BK; h += 16) {
            // A fragment: row rowBase+lar, ks t+lak+h .. +3
            size_t ai = (size_t)(rowBase + lar) * N + t + lak + h;
            float4 av = *(const float4*)(A0 + ai);
            if (A1) { float4 w = *(const float4*)(A1 + ai);
                      av.x += w.x; av.y += w.y; av.z += w.z; av.w += w.w; }
            if (A2) { float4 w = *(const float4*)(A2 + ai);
                      av.x += w.x; av.y += w.y; av.z += w.z; av.w += w.w; }
            if (A3) { float4 w = *(const float4*)(A3 + ai);
                      av.x += w.x; av.y += w.y; av.z += w.z; av.w += w.w; }
            // B fragment: row t+lbk+h, cols colBase+lbc .. +3
            size_t bi = (size_t)(t + lbk + h) * N + colBase + lbc;
            float4 bv = *(const float4*)(B0 + bi);
            if (B1) { float4 w = *(const float4*)(B1 + bi);
                      bv.x += w.x; bv.y += w.y; bv.z += w.z; bv.w += w.w; }
            if (B2) { float4 w = *(const float4*)(B2 + bi);
                      bv.x += w.x; bv.y += w.y; bv.z += w.z; bv.w += w.w; }
            if (B3) { float4 w = *(const float4*)(B3 + bi);
                      bv.x += w.x; bv.y += w.y; bv.z += w.z; bv.w += w.w; }
            if (addI) {
                int r = rowBase + lar, c = t + lak + h;
                if (r == c + 0) av.x += 1.0f;
                if (r == c + 1) av.y += 1.0f;
                if (r == c + 2) av.z += 1.0f;
                if (r == c + 3) av.w += 1.0f;
                int r2 = t + lbk + h, c2 = colBase + lbc;
                if (r2 == c2 + 0) bv.x += 1.0f;
                if (r2 == c2 + 1) bv.y += 1.0f;
                if (r2 == c2 + 2) bv.z += 1.0f;
                if (r2 == c2 + 3) bv.w += 1.0f;
            }
            As[lak + h + 0][lar] = av.x;
            As[lak + h + 1][lar] = av.y;
            As[lak + h + 2][lar] = av.z;
            As[lak + h + 3][lar] = av.w;
            *(float4*)&Bs[lbk + h][lbc] = bv;
        }
        __syncthreads();
#pragma unroll
        for (int k = 0; k < BK; ++k) {
            float4 a = *(const float4*)&As[k][ty * 4];
            float4 b = *(const float4*)&Bs[k][tx * 4];
            float avx[4] = {a.x, a.y, a.z, a.w};
            float bvx[4] = {b.x, b.y, b.z, b.w};
#pragma unroll
            for (int i = 0; i < 4; ++i)
#pragma unroll
                for (int j = 0; j < 4; ++j)
                    acc[i][j] += avx[i] * bvx[j];
        }
        __syncthreads();
    }
#pragma unroll
    for (int i = 0; i < 4; ++i)
        *(float4*)&C[(size_t)(rowBase + ty * 4 + i) * N + colBase + tx * 4] =
            make_float4(acc[i][0], acc[i][1], acc[i][2], acc[i][3]);
}

// remap[j] = 1 + max({j} U {i != j : M10[i][j] > 1}); classification symmetric
// (symmetric adjacency => symmetric counts; test exact in fp32) => read ROW j.
__global__ void k_remap(const float* __restrict__ R0, const float* __restrict__ R1,
                        const float* __restrict__ R2, const float* __restrict__ R3,
                        float* __restrict__ rmap, int N) {
    int j = blockIdx.x;
    int lane = threadIdx.x;  // 64
    size_t o = (size_t)j * N;
    int best = j;
    for (int i = lane; i < N; i += 64) {
        float v = R0[o + i];
        if (R1) v += R1[o + i];
        if (R2) v += R2[o + i];
        if (R3) v += R3[o + i];
        if (i != j && v > 1.0f && i > best) best = i;
    }
    for (int off = 32; off; off >>= 1) {
        int o2 = __shfl_down(best, off);
        if (o2 > best) best = o2;
    }
    if (lane == 0) rmap[j] = (float)(best + 1);
}

extern "C" void kernel_launch(void* const* d_in, const int* in_sizes, int n_in,
                              void* d_out, int out_size, void* d_ws, size_t ws_size,
                              hipStream_t stream) {
    const float* prob   = (const float*)d_in[0];
    const int*   coords = (const int*)d_in[1];
    const float* adj    = (const float*)d_in[2];
    const int*   dsz1   = (const int*)d_in[4];

    const int NE = in_sizes[0];            // N*h*w = 4718592
    const int NN = in_sizes[2];            // N*N
    int N = (int)(sqrt((double)NN) + 0.5); // 512
    const int HW = NE / N;                 // 9216
    const int total = out_size;            // 1048576
    const int NB1 = N - 1;
    const size_t bufB = (size_t)NN * 4;    // 1 MB
    const int NBUCK = (total + BPB - 1) / BPB;   // 1024

    const size_t cntB = (size_t)NBUCK * CNTSTRIDE * 4;       // 64 KB
    const size_t binB = (size_t)NBUCK * CAPN * 8;            // 32 MB
    char* ws = (char*)d_ws;

    const int nTiles = (N / BM) * (N / BM);   // 64
    const int kLen = N / 4;                   // split-K=4
    dim3 mg(nTiles * 4);
    float* Z = nullptr;

    if (ws_size >= cntB + binB + bufB * 16 + 4096) {
        // ---- binned path ----
        unsigned* gcnt = (unsigned*)ws;
        u64* buf = (u64*)(ws + cntB);
        size_t off = cntB + binB;
        float* m[16];
        for (int i = 0; i < 16; ++i) { m[i] = (float*)(ws + off); off += bufB; }
        float* rmap = (float*)(ws + off);

        hipMemsetAsync(gcnt, 0, cntB, stream);

        int NE4 = NE / 4;
        int i4PerBlk = (NE4 + NBLKA - 1) / NBLKA;
        k_binA<<<NBLKA, 256, 0, stream>>>(prob, coords, gcnt, buf,
                                          NE, HW / 4, NB1, dsz1,
                                          i4PerBlk, NBUCK);

        k_mm4<<<mg, 256, 0, stream>>>(adj, Z, Z, Z, adj, Z, Z, Z,
                                      m[0], m[1], m[2], m[3], N, 1, kLen);
        k_mm4<<<mg, 256, 0, stream>>>(m[0], m[1], m[2], m[3],
                                      m[0], m[1], m[2], m[3],
                                      m[4], m[5], m[6], m[7], N, 0, kLen);
        k_mm4<<<mg, 256, 0, stream>>>(m[4], m[5], m[6], m[7],
                                      m[4], m[5], m[6], m[7],
                                      m[8], m[9], m[10], m[11], N, 0, kLen);
        k_mm4<<<mg, 256, 0, stream>>>(m[8], m[9], m[10], m[11],
                                      m[0], m[1], m[2], m[3],
                                      m[12], m[13], m[14], m[15], N, 0, kLen);
        k_remap<<<N, 64, 0, stream>>>(m[12], m[13], m[14], m[15], rmap, N);

        k_binBfin<<<NBUCK, 256, 0, stream>>>(gcnt, buf, rmap,
                                             (float*)d_out, total, NB1);
    } else {
        // ---- fallback: direct atomics ----
        unsigned* packed = (unsigned*)ws;
        size_t off = (size_t)total * 4;
        float* m[16];
        for (int i = 0; i < 16; ++i) { m[i] = (float*)(ws + off); off += bufB; }
        float* rmap = (float*)(ws + off);

        hipMemsetAsync(packed, 0, (size_t)total * 4, stream);
        k_scatter<<<(NE / 4 + 255) / 256, 256, 0, stream>>>(
            prob, coords, packed, NE, HW / 4, NB1, dsz1);

        k_mm4<<<mg, 256, 0, stream>>>(adj, Z, Z, Z, adj, Z, Z, Z,
                                      m[0], m[1], m[2], m[3], N, 1, kLen);
        k_mm4<<<mg, 256, 0, stream>>>(m[0], m[1], m[2], m[3],
                                      m[0], m[1], m[2], m[3],
                                      m[4], m[5], m[6], m[7], N, 0, kLen);
        k_mm4<<<mg, 256, 0, stream>>>(m[4], m[5], m[6], m[7],
                                      m[4], m[5], m[6], m[7],
                                      m[8], m[9], m[10], m[11], N, 0, kLen);
        k_mm4<<<mg, 256, 0, stream>>>(m[8], m[9], m[10], m[11],
                                      m[0], m[1], m[2], m[3],
                                      m[12], m[13], m[14], m[15], N, 0, kLen);
        k_remap<<<N, 64, 0, stream>>>(m[12], m[13], m[14], m[15], rmap, N);
        k_finalize<<<(total / 4 + 255) / 256, 256, 0, stream>>>(
            packed, rmap, (float*)d_out, total, NB1);
    }
}

// Round 9
// 130.412 us; speedup vs baseline: 1.4484x; 1.1927x over previous
//
#include <hip/hip_runtime.h>
#include <math.h>

#define MASK_THR 0.53f
#define NBLKA 512       // binA blocks
#define CAPB 32         // slots per (block,bucket) slab
#define NBK 256         // max buckets
#define BSH 12          // bins per bucket = 4096
#define BMSK 4095
#define OVFCAP 4096

typedef unsigned long long u64;

// ---- binA v3: single pass, LDS slabs, zero global atomics. ----
// Packing: p in [0.53,1) => exponent fixed 126 => mantissa orders as p.
// Output needs only winner's instance n => val=(mant<<9)|(NB1-n):
// max val = max p, tie -> min n. val always nonzero for candidates.
__global__ __launch_bounds__(256) void k_binA(
        const float* __restrict__ prob, const int* __restrict__ coords,
        unsigned* __restrict__ cnt, u64* __restrict__ buf,
        unsigned* __restrict__ ovf_cnt, u64* __restrict__ ovf,
        int NE, int HW4, int NB1, const int* __restrict__ d_size1,
        int i4PerBlk, int nbuck) {
    __shared__ u64 slab[NBK * CAPB];     // 64 KB
    __shared__ unsigned hist[NBK];
    int tid = threadIdx.x, blk = blockIdx.x;
    for (int i = tid; i < NBK; i += 256) hist[i] = 0u;
    __syncthreads();
    int size1 = *d_size1;
    int NE4 = NE >> 2;
    int i4Base = blk * i4PerBlk;
    int i4End = min(i4Base + i4PerBlk, NE4);
    for (int i4 = i4Base + tid; i4 < i4End; i4 += 256) {
        float4 p = ((const float4*)prob)[i4];
        int4 x = ((const int4*)coords)[i4];
        int4 y = ((const int4*)(coords + NE))[i4];
        unsigned n = (unsigned)i4 / (unsigned)HW4;   // HW%4==0: 4 px share n
        unsigned tie = (unsigned)(NB1 - (int)n);
        float pv[4] = {p.x, p.y, p.z, p.w};
        int   xv[4] = {x.x, x.y, x.z, x.w};
        int   yv[4] = {y.x, y.y, y.z, y.w};
#pragma unroll
        for (int e = 0; e < 4; ++e)
            if (pv[e] >= MASK_THR) {
                unsigned key = (unsigned)(xv[e] * size1 + yv[e]);
                unsigned b = key >> BSH;
                unsigned v = ((__float_as_uint(pv[e]) & 0x7FFFFFu) << 9) | tie;
                unsigned pos = atomicAdd(&hist[b], 1u);
                if (pos < CAPB)
                    slab[b * CAPB + pos] = ((u64)(key & BMSK) << 32) | v;
                else {
                    unsigned g = atomicAdd(ovf_cnt, 1u);
                    if (g < OVFCAP) ovf[g] = ((u64)key << 32) | v;
                }
            }
    }
    __syncthreads();
    // clamp counts, publish (plain coalesced stores), keep clamped in hist
    for (int b = tid; b < nbuck; b += 256) {
        unsigned c = hist[b];
        if (c > CAPB) c = CAPB;
        cnt[(size_t)blk * NBK + b] = c;
        hist[b] = c;
    }
    __syncthreads();
    // dump: sequential masked sweep -> contiguous per-block 64KB region
    for (int j = tid; j < NBK * CAPB; j += 256) {
        int b = j >> 5, s = j & (CAPB - 1);
        if (s < (int)hist[b])
            buf[((size_t)blk * NBK + b) * CAPB + s] = slab[j];
    }
}

// ---- binBfin v2: block b merges bucket b from all slabs via LDS atomicMax,
// merges overflow, writes output segment [b<<BSH, (b+1)<<BSH) through rmap. ----
__global__ __launch_bounds__(256) void k_binBfin(
        const unsigned* __restrict__ cnt, const u64* __restrict__ buf,
        const unsigned* __restrict__ ovf_cnt, const u64* __restrict__ ovf,
        const float* __restrict__ rmap, float* __restrict__ out,
        int total, int NB1) {
    __shared__ unsigned bins[1 << BSH];  // 16 KB
    __shared__ unsigned lc[NBLKA];       // 2 KB
    int b = blockIdx.x, tid = threadIdx.x;
    for (int i = tid; i < (1 << BSH); i += 256) bins[i] = 0u;
    for (int s = tid; s < NBLKA; s += 256) lc[s] = cnt[(size_t)s * NBK + b];
    __syncthreads();
    for (int j = tid; j < NBLKA * CAPB; j += 256) {
        int s = j >> 5, slot = j & (CAPB - 1);
        if (slot < (int)lc[s]) {
            u64 kv = buf[((size_t)s * NBK + b) * CAPB + slot];
            atomicMax(&bins[(unsigned)(kv >> 32)], (unsigned)kv);
        }
    }
    unsigned oc = *ovf_cnt;
    if (oc > OVFCAP) oc = OVFCAP;
    for (unsigned i = tid; i < oc; i += 256) {
        u64 kv = ovf[i];
        unsigned key = (unsigned)(kv >> 32);
        if ((int)(key >> BSH) == b)
            atomicMax(&bins[key & BMSK], (unsigned)kv);
    }
    __syncthreads();
    int base = b << BSH;
    for (int i = tid; i < (1 << BSH); i += 256) {
        int g = base + i;
        if (g < total) {
            unsigned v = bins[i];
            out[g] = v ? rmap[NB1 - (int)(v & 0x1FFu)] : 0.0f;
        }
    }
}

// ---- Fallback: direct-atomic scatter + finalize (proven, ~90us) ----
__global__ __launch_bounds__(256) void k_scatter(
        const float* __restrict__ prob, const int* __restrict__ coords,
        unsigned* __restrict__ packed, int NE, int HW4, int NB1,
        const int* __restrict__ d_size1) {
    int i4 = blockIdx.x * blockDim.x + threadIdx.x;
    if (i4 * 4 >= NE) return;
    int size1 = *d_size1;
    float4 p = ((const float4*)prob)[i4];
    int4 x = ((const int4*)coords)[i4];
    int4 y = ((const int4*)(coords + NE))[i4];
    unsigned n = (unsigned)i4 / (unsigned)HW4;
    unsigned tie = (unsigned)(NB1 - (int)n);
    float pv[4] = {p.x, p.y, p.z, p.w};
    int   xv[4] = {x.x, x.y, x.z, x.w};
    int   yv[4] = {y.x, y.y, y.z, y.w};
#pragma unroll
    for (int e = 0; e < 4; ++e)
        if (pv[e] >= MASK_THR) {
            unsigned v = ((__float_as_uint(pv[e]) & 0x7FFFFFu) << 9) | tie;
            atomicMax(&packed[xv[e] * size1 + yv[e]], v);
        }
}

__global__ void k_finalize(const unsigned* __restrict__ packed,
                           const float* __restrict__ rmap,
                           float* __restrict__ out, int total, int NB1) {
    int i4 = blockIdx.x * blockDim.x + threadIdx.x;
    if (i4 * 4 >= total) return;
    uint4 u = ((const uint4*)packed)[i4];
    unsigned v[4] = {u.x, u.y, u.z, u.w};
    float o[4];
#pragma unroll
    for (int e = 0; e < 4; ++e)
        o[e] = v[e] ? rmap[NB1 - (int)(v[e] & 0x1FFu)] : 0.0f;
    ((float4*)out)[i4] = make_float4(o[0], o[1], o[2], o[3]);
}

// ---- matmul: 64x64 tile, 4x4/thread, A transposed in LDS (ds_read_b128 both
// operands), split-K=4, inputs = sum of up to 4 partials (exact: integer fp32
// < 2^24), optional +I. >1 classification exact in fp32. ----
#define BM 64
#define BK 32
#define LSTR 68
__global__ __launch_bounds__(256) void k_mm4(
        const float* __restrict__ A0, const float* __restrict__ A1,
        const float* __restrict__ A2, const float* __restrict__ A3,
        const float* __restrict__ B0, const float* __restrict__ B1,
        const float* __restrict__ B2, const float* __restrict__ B3,
        float* __restrict__ C0, float* __restrict__ C1,
        float* __restrict__ C2, float* __restrict__ C3,
        int N, int addI, int kLen) {
    __shared__ float As[BK][LSTR];
    __shared__ float Bs[BK][LSTR];
    int NT = N / BM;
    int nTiles = NT * NT;
    int bid = blockIdx.x % nTiles;
    int sp  = blockIdx.x / nTiles;
    int kBase = sp * kLen;
    float* C = sp == 0 ? C0 : sp == 1 ? C1 : sp == 2 ? C2 : C3;
    int tid = threadIdx.x;
    int bx = bid % NT, by = bid / NT;
    int rowBase = by * BM, colBase = bx * BM;
    int tx = tid & 15, ty = tid >> 4;
    int lar = tid & 63;
    int lak = (tid >> 6) * 4;
    int lbk = tid >> 4;
    int lbc = (tid & 15) * 4;
    float acc[4][4] = {{0}};
    for (int t = kBase; t < kBase + kLen; t += BK) {
#pragma unroll
        for (int h = 0; h < BK; h += 16) {
            size_t ai = (size_t)(rowBase + lar) * N + t + lak + h;
            float4 av = *(const float4*)(A0 + ai);
            if (A1) { float4 w = *(const float4*)(A1 + ai);
                      av.x += w.x; av.y += w.y; av.z += w.z; av.w += w.w; }
            if (A2) { float4 w = *(const float4*)(A2 + ai);
                      av.x += w.x; av.y += w.y; av.z += w.z; av.w += w.w; }
            if (A3) { float4 w = *(const float4*)(A3 + ai);
                      av.x += w.x; av.y += w.y; av.z += w.z; av.w += w.w; }
            size_t bi = (size_t)(t + lbk + h) * N + colBase + lbc;
            float4 bv = *(const float4*)(B0 + bi);
            if (B1) { float4 w = *(const float4*)(B1 + bi);
                      bv.x += w.x; bv.y += w.y; bv.z += w.z; bv.w += w.w; }
            if (B2) { float4 w = *(const float4*)(B2 + bi);
                      bv.x += w.x; bv.y += w.y; bv.z += w.z; bv.w += w.w; }
            if (B3) { float4 w = *(const float4*)(B3 + bi);
                      bv.x += w.x; bv.y += w.y; bv.z += w.z; bv.w += w.w; }
            if (addI) {
                int r = rowBase + lar, c = t + lak + h;
                if (r == c + 0) av.x += 1.0f;
                if (r == c + 1) av.y += 1.0f;
                if (r == c + 2) av.z += 1.0f;
                if (r == c + 3) av.w += 1.0f;
                int r2 = t + lbk + h, c2 = colBase + lbc;
                if (r2 == c2 + 0) bv.x += 1.0f;
                if (r2 == c2 + 1) bv.y += 1.0f;
                if (r2 == c2 + 2) bv.z += 1.0f;
                if (r2 == c2 + 3) bv.w += 1.0f;
            }
            As[lak + h + 0][lar] = av.x;
            As[lak + h + 1][lar] = av.y;
            As[lak + h + 2][lar] = av.z;
            As[lak + h + 3][lar] = av.w;
            *(float4*)&Bs[lbk + h][lbc] = bv;
        }
        __syncthreads();
#pragma unroll
        for (int k = 0; k < BK; ++k) {
            float4 a = *(const float4*)&As[k][ty * 4];
            float4 b = *(const float4*)&Bs[k][tx * 4];
            float avx[4] = {a.x, a.y, a.z, a.w};
            float bvx[4] = {b.x, b.y, b.z, b.w};
#pragma unroll
            for (int i = 0; i < 4; ++i)
#pragma unroll
                for (int j = 0; j < 4; ++j)
                    acc[i][j] += avx[i] * bvx[j];
        }
        __syncthreads();
    }
#pragma unroll
    for (int i = 0; i < 4; ++i)
        *(float4*)&C[(size_t)(rowBase + ty * 4 + i) * N + colBase + tx * 4] =
            make_float4(acc[i][0], acc[i][1], acc[i][2], acc[i][3]);
}

// remap[j] = 1 + max({j} U {i != j : M10[i][j] > 1}); symmetric => read ROW j.
__global__ void k_remap(const float* __restrict__ R0, const float* __restrict__ R1,
                        const float* __restrict__ R2, const float* __restrict__ R3,
                        float* __restrict__ rmap, int N) {
    int j = blockIdx.x;
    int lane = threadIdx.x;  // 64
    size_t o = (size_t)j * N;
    int best = j;
    for (int i = lane; i < N; i += 64) {
        float v = R0[o + i];
        if (R1) v += R1[o + i];
        if (R2) v += R2[o + i];
        if (R3) v += R3[o + i];
        if (i != j && v > 1.0f && i > best) best = i;
    }
    for (int off = 32; off; off >>= 1) {
        int o2 = __shfl_down(best, off);
        if (o2 > best) best = o2;
    }
    if (lane == 0) rmap[j] = (float)(best + 1);
}

extern "C" void kernel_launch(void* const* d_in, const int* in_sizes, int n_in,
                              void* d_out, int out_size, void* d_ws, size_t ws_size,
                              hipStream_t stream) {
    const float* prob   = (const float*)d_in[0];
    const int*   coords = (const int*)d_in[1];
    const float* adj    = (const float*)d_in[2];
    const int*   dsz1   = (const int*)d_in[4];

    const int NE = in_sizes[0];            // 4718592
    const int NN = in_sizes[2];            // 512*512
    int N = (int)(sqrt((double)NN) + 0.5); // 512
    const int HW = NE / N;                 // 9216
    const int total = out_size;            // 1048576
    const int NB1 = N - 1;
    const size_t bufB = (size_t)NN * 4;    // 1 MB
    const int nbuck = (total + BMSK) >> BSH;

    char* ws = (char*)d_ws;
    const size_t slabB = (size_t)NBLKA * NBK * CAPB * 8;   // 33.5 MB
    const size_t cntB  = (size_t)NBLKA * NBK * 4;          // 512 KB
    const size_t ovfB  = 64 + (size_t)OVFCAP * 8;          // ~32 KB
    const size_t needBin = slabB + cntB + ovfB + bufB * 12 + 4096;

    const int nTiles = (N / BM) * (N / BM);   // 64
    const int kLen = N / 4;
    dim3 mg(nTiles * 4);
    float* Z = nullptr;

    bool binOK = (nbuck <= NBK) && (NE % 4 == 0) && (HW % 4 == 0) &&
                 (ws_size >= needBin);

    if (binOK) {
        u64* buf = (u64*)ws;
        unsigned* cnt = (unsigned*)(ws + slabB);
        unsigned* ovf_cnt = (unsigned*)(ws + slabB + cntB);
        u64* ovf = (u64*)(ws + slabB + cntB + 64);
        size_t off = slabB + cntB + ovfB;
        float* m[12];
        for (int i = 0; i < 12; ++i) { m[i] = (float*)(ws + off); off += bufB; }
        float* rmap = (float*)(ws + off);

        hipMemsetAsync(ovf_cnt, 0, 4, stream);

        int NE4 = NE / 4;
        int i4PerBlk = (NE4 + NBLKA - 1) / NBLKA;
        k_binA<<<NBLKA, 256, 0, stream>>>(prob, coords, cnt, buf, ovf_cnt, ovf,
                                          NE, HW / 4, NB1, dsz1, i4PerBlk,
                                          nbuck);

        // P2=m[0..3], P4=m[4..7], P8=m[8..11], P10->m[4..7] (P4 dead)
        k_mm4<<<mg, 256, 0, stream>>>(adj, Z, Z, Z, adj, Z, Z, Z,
                                      m[0], m[1], m[2], m[3], N, 1, kLen);
        k_mm4<<<mg, 256, 0, stream>>>(m[0], m[1], m[2], m[3],
                                      m[0], m[1], m[2], m[3],
                                      m[4], m[5], m[6], m[7], N, 0, kLen);
        k_mm4<<<mg, 256, 0, stream>>>(m[4], m[5], m[6], m[7],
                                      m[4], m[5], m[6], m[7],
                                      m[8], m[9], m[10], m[11], N, 0, kLen);
        k_mm4<<<mg, 256, 0, stream>>>(m[8], m[9], m[10], m[11],
                                      m[0], m[1], m[2], m[3],
                                      m[4], m[5], m[6], m[7], N, 0, kLen);
        k_remap<<<N, 64, 0, stream>>>(m[4], m[5], m[6], m[7], rmap, N);

        k_binBfin<<<nbuck, 256, 0, stream>>>(cnt, buf, ovf_cnt, ovf, rmap,
                                             (float*)d_out, total, NB1);
    } else {
        unsigned* packed = (unsigned*)ws;
        size_t off = (size_t)total * 4;
        float* m[12];
        for (int i = 0; i < 12; ++i) { m[i] = (float*)(ws + off); off += bufB; }
        float* rmap = (float*)(ws + off);

        hipMemsetAsync(packed, 0, (size_t)total * 4, stream);
        k_scatter<<<(NE / 4 + 255) / 256, 256, 0, stream>>>(
            prob, coords, packed, NE, HW / 4, NB1, dsz1);

        k_mm4<<<mg, 256, 0, stream>>>(adj, Z, Z, Z, adj, Z, Z, Z,
                                      m[0], m[1], m[2], m[3], N, 1, kLen);
        k_mm4<<<mg, 256, 0, stream>>>(m[0], m[1], m[2], m[3],
                                      m[0], m[1], m[2], m[3],
                                      m[4], m[5], m[6], m[7], N, 0, kLen);
        k_mm4<<<mg, 256, 0, stream>>>(m[4], m[5], m[6], m[7],
                                      m[4], m[5], m[6], m[7],
                                      m[8], m[9], m[10], m[11], N, 0, kLen);
        k_mm4<<<mg, 256, 0, stream>>>(m[8], m[9], m[10], m[11],
                                      m[0], m[1], m[2], m[3],
                                      m[4], m[5], m[6], m[7], N, 0, kLen);
        k_remap<<<N, 64, 0, stream>>>(m[4], m[5], m[6], m[7], rmap, N);
        k_finalize<<<(total / 4 + 255) / 256, 256, 0, stream>>>(
            packed, rmap, (float*)d_out, total, NB1);
    }
}

// Round 10
// 79.848 us; speedup vs baseline: 2.3656x; 1.6333x over previous
//
#include <hip/hip_runtime.h>
#include <math.h>

#define MASK_THR 0.53f
#define NBLKA 512       // binA blocks
#define BLKA_THR 512    // binA threads/block
#define CAPB 32         // slots per (block,bucket) slab
#define NBK 256         // max buckets
#define BSH 12          // bins per bucket = 4096
#define BMSK 4095
#define OVFC 64         // per-block overflow cap
#define DEGCAP 64       // CSR cap per node

typedef unsigned long long u64;

// ---- binA: single pass, LDS slabs, zero global atomics, fused CSR build. --
// Packing: p in [0.53,1) => exponent fixed 126 => mantissa orders as p.
// Output needs only winner's instance n => val=(mant<<9)|(NB1-n):
// max val = max p, tie -> min n. val always nonzero for candidates.
__global__ __launch_bounds__(BLKA_THR) void k_binA(
        const float* __restrict__ prob, const int* __restrict__ coords,
        const float* __restrict__ adj,
        unsigned* __restrict__ cnt, u64* __restrict__ buf,
        unsigned* __restrict__ ovfcnt, u64* __restrict__ ovf,
        unsigned* __restrict__ deg, int* __restrict__ cols,
        int NE, int HW4, int NB1, const int* __restrict__ d_size1,
        int i4PerBlk, int nbuck, int N) {
    __shared__ u64 slab[NBK * CAPB];     // 64 KB
    __shared__ unsigned hist[NBK];
    __shared__ unsigned lcnt, ocnt;
    int tid = threadIdx.x, blk = blockIdx.x;
    for (int i = tid; i < NBK; i += BLKA_THR) hist[i] = 0u;
    if (tid == 0) { lcnt = 0u; ocnt = 0u; }
    __syncthreads();
    // fused CSR build: block blk scans adjacency row blk (order-free: the
    // walk sums are exact integer fp32 adds => commutative).
    if (blk < N) {
        for (int c = tid; c < N; c += BLKA_THR)
            if (adj[(size_t)blk * N + c] != 0.0f) {
                unsigned pos = atomicAdd(&lcnt, 1u);
                if (pos < DEGCAP) cols[(size_t)blk * DEGCAP + pos] = c;
            }
    }
    // scatter into LDS slab
    int size1 = *d_size1;
    int NE4 = NE >> 2;
    int i4Base = blk * i4PerBlk;
    int i4End = min(i4Base + i4PerBlk, NE4);
    for (int i4 = i4Base + tid; i4 < i4End; i4 += BLKA_THR) {
        float4 p = ((const float4*)prob)[i4];
        int4 x = ((const int4*)coords)[i4];
        int4 y = ((const int4*)(coords + NE))[i4];
        unsigned n = (unsigned)i4 / (unsigned)HW4;   // HW%4==0: 4 px share n
        unsigned tie = (unsigned)(NB1 - (int)n);
        float pv[4] = {p.x, p.y, p.z, p.w};
        int   xv[4] = {x.x, x.y, x.z, x.w};
        int   yv[4] = {y.x, y.y, y.z, y.w};
#pragma unroll
        for (int e = 0; e < 4; ++e)
            if (pv[e] >= MASK_THR) {
                unsigned key = (unsigned)(xv[e] * size1 + yv[e]);
                unsigned b = key >> BSH;
                unsigned v = ((__float_as_uint(pv[e]) & 0x7FFFFFu) << 9) | tie;
                unsigned pos = atomicAdd(&hist[b], 1u);
                if (pos < CAPB)
                    slab[b * CAPB + pos] = ((u64)(key & BMSK) << 32) | v;
                else {
                    unsigned g = atomicAdd(&ocnt, 1u);
                    if (g < OVFC) ovf[(size_t)blk * OVFC + g] =
                        ((u64)key << 32) | v;
                }
            }
    }
    __syncthreads();
    if (tid == 0) {
        ovfcnt[blk] = min(ocnt, (unsigned)OVFC);
        if (blk < N) deg[blk] = min(lcnt, (unsigned)DEGCAP);
    }
    // clamp + publish counts (plain coalesced stores; no global RMW anywhere)
    for (int b = tid; b < nbuck; b += BLKA_THR) {
        unsigned c = hist[b];
        if (c > CAPB) c = CAPB;
        cnt[(size_t)blk * NBK + b] = c;
        hist[b] = c;
    }
    __syncthreads();
    // dump slab -> per-block contiguous region
    for (int j = tid; j < NBK * CAPB; j += BLKA_THR) {
        int b = j >> 5, s = j & (CAPB - 1);
        if (s < (int)hist[b])
            buf[((size_t)blk * NBK + b) * CAPB + s] = slab[j];
    }
}

// ---- k_walk: one block per node. v <- (I+A) v, 10 times, in LDS; then
// remap[i] = 1 + max({i} U {j != i : v[j] > 1}). Exactness: all counts are
// nonneg integers; 0/1 entries are sums of tiny exact terms (exact in fp32
// in both this and the reference's matmuls); entries >= 2 can round but
// never below the >1 threshold => classification identical to reference. ----
__global__ __launch_bounds__(256) void k_walk(
        const unsigned* __restrict__ deg, const int* __restrict__ cols,
        float* __restrict__ rmap, int N) {
    __shared__ float v0[512], v1[512];
    __shared__ int red[4];
    int i = blockIdx.x, tid = threadIdx.x;
    for (int j = tid; j < N; j += 256) v0[j] = (j == i) ? 1.0f : 0.0f;
    __syncthreads();
    float* cur = v0; float* nxt = v1;
    for (int it = 0; it < 10; ++it) {
        for (int j = tid; j < N; j += 256) {
            float s = cur[j];
            unsigned d = deg[j];
            const int* cj = cols + (size_t)j * DEGCAP;
            for (unsigned k = 0; k < d; ++k) s += cur[cj[k]];
            nxt[j] = s;
        }
        __syncthreads();
        float* t = cur; cur = nxt; nxt = t;
    }
    int best = i;
    for (int j = tid; j < N; j += 256)
        if (j != i && cur[j] > 1.0f && j > best) best = j;
    for (int off = 32; off; off >>= 1) {
        int o = __shfl_down(best, off);
        if (o > best) best = o;
    }
    if ((tid & 63) == 0) red[tid >> 6] = best;
    __syncthreads();
    if (tid == 0) {
        for (int w = 1; w < 4; ++w) if (red[w] > best) best = red[w];
        rmap[i] = (float)(best + 1);
    }
}

// ---- binBfin: block b merges bucket b from all slabs + overflow lists via
// LDS atomicMax, writes output segment [b<<BSH,(b+1)<<BSH) through rmap. ----
__global__ __launch_bounds__(256) void k_binBfin(
        const unsigned* __restrict__ cnt, const u64* __restrict__ buf,
        const unsigned* __restrict__ ovfcnt, const u64* __restrict__ ovf,
        const float* __restrict__ rmap, float* __restrict__ out,
        int total, int NB1) {
    __shared__ unsigned bins[1 << BSH];  // 16 KB
    __shared__ unsigned lc[NBLKA];       // 2 KB
    __shared__ unsigned oc[NBLKA];       // 2 KB
    int b = blockIdx.x, tid = threadIdx.x;
    for (int i = tid; i < (1 << BSH); i += 256) bins[i] = 0u;
    for (int s = tid; s < NBLKA; s += 256) {
        lc[s] = cnt[(size_t)s * NBK + b];
        oc[s] = ovfcnt[s];
    }
    __syncthreads();
    for (int j = tid; j < NBLKA * CAPB; j += 256) {
        int s = j >> 5, slot = j & (CAPB - 1);
        if (slot < (int)lc[s]) {
            u64 kv = buf[((size_t)s * NBK + b) * CAPB + slot];
            atomicMax(&bins[(unsigned)(kv >> 32)], (unsigned)kv);
        }
    }
    for (int j = tid; j < NBLKA * OVFC; j += 256) {
        int s = j / OVFC, e = j % OVFC;
        if (e < (int)oc[s]) {
            u64 kv = ovf[(size_t)s * OVFC + e];
            unsigned key = (unsigned)(kv >> 32);
            if ((int)(key >> BSH) == b)
                atomicMax(&bins[key & BMSK], (unsigned)kv);
        }
    }
    __syncthreads();
    int base = b << BSH;
    for (int i = tid; i < (1 << BSH); i += 256) {
        int g = base + i;
        if (g < total) {
            unsigned v = bins[i];
            out[g] = v ? rmap[NB1 - (int)(v & 0x1FFu)] : 0.0f;
        }
    }
}

// ---- Fallback path (ws too small): direct atomics + separate edges ----
__global__ __launch_bounds__(256) void k_scatter(
        const float* __restrict__ prob, const int* __restrict__ coords,
        unsigned* __restrict__ packed, int NE, int HW4, int NB1,
        const int* __restrict__ d_size1) {
    int i4 = blockIdx.x * blockDim.x + threadIdx.x;
    if (i4 * 4 >= NE) return;
    int size1 = *d_size1;
    float4 p = ((const float4*)prob)[i4];
    int4 x = ((const int4*)coords)[i4];
    int4 y = ((const int4*)(coords + NE))[i4];
    unsigned n = (unsigned)i4 / (unsigned)HW4;
    unsigned tie = (unsigned)(NB1 - (int)n);
    float pv[4] = {p.x, p.y, p.z, p.w};
    int   xv[4] = {x.x, x.y, x.z, x.w};
    int   yv[4] = {y.x, y.y, y.z, y.w};
#pragma unroll
    for (int e = 0; e < 4; ++e)
        if (pv[e] >= MASK_THR) {
            unsigned v = ((__float_as_uint(pv[e]) & 0x7FFFFFu) << 9) | tie;
            atomicMax(&packed[xv[e] * size1 + yv[e]], v);
        }
}

__global__ void k_edges(const float* __restrict__ adj, unsigned* __restrict__ deg,
                        int* __restrict__ cols, int N) {
    __shared__ unsigned lcnt;
    int r = blockIdx.x, tid = threadIdx.x;
    if (tid == 0) lcnt = 0u;
    __syncthreads();
    for (int c = tid; c < N; c += blockDim.x)
        if (adj[(size_t)r * N + c] != 0.0f) {
            unsigned pos = atomicAdd(&lcnt, 1u);
            if (pos < DEGCAP) cols[(size_t)r * DEGCAP + pos] = c;
        }
    __syncthreads();
    if (tid == 0) deg[r] = min(lcnt, (unsigned)DEGCAP);
}

__global__ void k_finalize(const unsigned* __restrict__ packed,
                           const float* __restrict__ rmap,
                           float* __restrict__ out, int total, int NB1) {
    int i4 = blockIdx.x * blockDim.x + threadIdx.x;
    if (i4 * 4 >= total) return;
    uint4 u = ((const uint4*)packed)[i4];
    unsigned v[4] = {u.x, u.y, u.z, u.w};
    float o[4];
#pragma unroll
    for (int e = 0; e < 4; ++e)
        o[e] = v[e] ? rmap[NB1 - (int)(v[e] & 0x1FFu)] : 0.0f;
    ((float4*)out)[i4] = make_float4(o[0], o[1], o[2], o[3]);
}

extern "C" void kernel_launch(void* const* d_in, const int* in_sizes, int n_in,
                              void* d_out, int out_size, void* d_ws, size_t ws_size,
                              hipStream_t stream) {
    const float* prob   = (const float*)d_in[0];
    const int*   coords = (const int*)d_in[1];
    const float* adj    = (const float*)d_in[2];
    const int*   dsz1   = (const int*)d_in[4];

    const int NE = in_sizes[0];            // 4718592
    const int NN = in_sizes[2];            // 512*512
    int N = (int)(sqrt((double)NN) + 0.5); // 512
    const int HW = NE / N;                 // 9216
    const int total = out_size;            // 1048576
    const int NB1 = N - 1;
    const int nbuck = (total + BMSK) >> BSH;   // 256

    char* ws = (char*)d_ws;
    const size_t slabB = (size_t)NBLKA * NBK * CAPB * 8;   // 33.55 MB
    const size_t cntB  = (size_t)NBLKA * NBK * 4;          // 512 KB
    const size_t ocB   = (size_t)NBLKA * 4;                // 2 KB
    const size_t ovfB  = (size_t)NBLKA * OVFC * 8;         // 256 KB
    const size_t colB  = (size_t)512 * DEGCAP * 4;         // 128 KB
    const size_t degB  = 512 * 4;
    const size_t rmapB = 512 * 4;
    const size_t needBin = slabB + cntB + ocB + ovfB + colB + degB + rmapB + 256;

    bool binOK = (nbuck <= NBK) && (N <= 512) && (N <= NBLKA) &&
                 (NE % 4 == 0) && (HW % 4 == 0) && (ws_size >= needBin);

    if (binOK) {
        size_t off = 0;
        u64* buf = (u64*)(ws + off); off += slabB;
        unsigned* cnt = (unsigned*)(ws + off); off += cntB;
        unsigned* ovfcnt = (unsigned*)(ws + off); off += ocB;
        u64* ovf = (u64*)(ws + off); off += ovfB;
        int* cols = (int*)(ws + off); off += colB;
        unsigned* deg = (unsigned*)(ws + off); off += degB;
        float* rmap = (float*)(ws + off);

        int NE4 = NE / 4;
        int i4PerBlk = (NE4 + NBLKA - 1) / NBLKA;
        k_binA<<<NBLKA, BLKA_THR, 0, stream>>>(
            prob, coords, adj, cnt, buf, ovfcnt, ovf, deg, cols,
            NE, HW / 4, NB1, dsz1, i4PerBlk, nbuck, N);

        k_walk<<<N, 256, 0, stream>>>(deg, cols, rmap, N);

        k_binBfin<<<nbuck, 256, 0, stream>>>(cnt, buf, ovfcnt, ovf, rmap,
                                             (float*)d_out, total, NB1);
    } else {
        unsigned* packed = (unsigned*)ws;
        size_t off = (size_t)total * 4;
        int* cols = (int*)(ws + off); off += colB;
        unsigned* deg = (unsigned*)(ws + off); off += degB;
        float* rmap = (float*)(ws + off);

        hipMemsetAsync(packed, 0, (size_t)total * 4, stream);
        k_scatter<<<(NE / 4 + 255) / 256, 256, 0, stream>>>(
            prob, coords, packed, NE, HW / 4, NB1, dsz1);
        k_edges<<<N, 256, 0, stream>>>(adj, deg, cols, N);
        k_walk<<<N, 256, 0, stream>>>(deg, cols, rmap, N);
        k_finalize<<<(total / 4 + 255) / 256, 256, 0, stream>>>(
            packed, rmap, (float*)d_out, total, NB1);
    }
}

// Round 11
// 54.445 us; speedup vs baseline: 3.4693x; 1.4666x over previous
//
#include <hip/hip_runtime.h>
#include <math.h>

#define MASK_THR 0.53f
#define NBLKA 512       // binA blocks
#define BLKA_THR 1024   // binA threads/block (64KB slab -> 2 blk/CU -> 32 waves)
#define BFIN_THR 1024   // binBfin threads/block (16 waves/CU vs 4: latency fix)
#define CAPB 32         // slots per (block,bucket) slab
#define NBK 256         // max buckets
#define BSH 12          // bins per bucket = 4096
#define BMSK 4095
#define OVFC 64         // per-block overflow cap
#define DEGCAP 64       // CSR cap per node

typedef unsigned long long u64;

// ---- binA: single pass, LDS slabs, zero global atomics, fused CSR build. --
// Packing: p in [0.53,1) => exponent fixed 126 => mantissa orders as p.
// Output needs only winner's instance n => val=(mant<<9)|(NB1-n):
// max val = max p, tie -> min n. val always nonzero for candidates.
__global__ __launch_bounds__(BLKA_THR) void k_binA(
        const float* __restrict__ prob, const int* __restrict__ coords,
        const float* __restrict__ adj,
        unsigned* __restrict__ cnt, u64* __restrict__ buf,
        unsigned* __restrict__ ovfcnt, u64* __restrict__ ovf,
        unsigned* __restrict__ deg, int* __restrict__ cols,
        int NE, int HW4, int NB1, const int* __restrict__ d_size1,
        int i4PerBlk, int nbuck, int N) {
    __shared__ u64 slab[NBK * CAPB];     // 64 KB
    __shared__ unsigned hist[NBK];
    __shared__ unsigned lcnt, ocnt;
    int tid = threadIdx.x, blk = blockIdx.x;
    for (int i = tid; i < NBK; i += BLKA_THR) hist[i] = 0u;
    if (tid == 0) { lcnt = 0u; ocnt = 0u; }
    __syncthreads();
    // fused CSR build: block blk scans adjacency row blk (order-free: the
    // walk sums are exact integer fp32 adds => commutative).
    if (blk < N) {
        for (int c = tid; c < N; c += BLKA_THR)
            if (adj[(size_t)blk * N + c] != 0.0f) {
                unsigned pos = atomicAdd(&lcnt, 1u);
                if (pos < DEGCAP) cols[(size_t)blk * DEGCAP + pos] = c;
            }
    }
    // scatter into LDS slab
    int size1 = *d_size1;
    int NE4 = NE >> 2;
    int i4Base = blk * i4PerBlk;
    int i4End = min(i4Base + i4PerBlk, NE4);
    for (int i4 = i4Base + tid; i4 < i4End; i4 += BLKA_THR) {
        float4 p = ((const float4*)prob)[i4];
        float pv[4] = {p.x, p.y, p.z, p.w};
        bool any = (pv[0] >= MASK_THR) | (pv[1] >= MASK_THR) |
                   (pv[2] >= MASK_THR) | (pv[3] >= MASK_THR);
        if (!any) continue;   // skip coord loads (~8% of groups all-fail)
        int4 x = ((const int4*)coords)[i4];
        int4 y = ((const int4*)(coords + NE))[i4];
        unsigned n = (unsigned)i4 / (unsigned)HW4;   // HW%4==0: 4 px share n
        unsigned tie = (unsigned)(NB1 - (int)n);
        int   xv[4] = {x.x, x.y, x.z, x.w};
        int   yv[4] = {y.x, y.y, y.z, y.w};
#pragma unroll
        for (int e = 0; e < 4; ++e)
            if (pv[e] >= MASK_THR) {
                unsigned key = (unsigned)(xv[e] * size1 + yv[e]);
                unsigned b = key >> BSH;
                unsigned v = ((__float_as_uint(pv[e]) & 0x7FFFFFu) << 9) | tie;
                unsigned pos = atomicAdd(&hist[b], 1u);
                if (pos < CAPB)
                    slab[b * CAPB + pos] = ((u64)(key & BMSK) << 32) | v;
                else {
                    unsigned g = atomicAdd(&ocnt, 1u);
                    if (g < OVFC) ovf[(size_t)blk * OVFC + g] =
                        ((u64)key << 32) | v;
                }
            }
    }
    __syncthreads();
    if (tid == 0) {
        ovfcnt[blk] = min(ocnt, (unsigned)OVFC);
        if (blk < N) deg[blk] = min(lcnt, (unsigned)DEGCAP);
    }
    // clamp + publish counts (plain coalesced stores; no global RMW anywhere)
    for (int b = tid; b < nbuck; b += BLKA_THR) {
        unsigned c = hist[b];
        if (c > CAPB) c = CAPB;
        cnt[(size_t)blk * NBK + b] = c;
        hist[b] = c;
    }
    __syncthreads();
    // dump slab -> per-block contiguous region
    for (int j = tid; j < NBK * CAPB; j += BLKA_THR) {
        int b = j >> 5, s = j & (CAPB - 1);
        if (s < (int)hist[b])
            buf[((size_t)blk * NBK + b) * CAPB + s] = slab[j];
    }
}

// ---- k_walk: one block per node. v <- (I+A) v, 10 times, in LDS; then
// remap[i] = 1 + max({i} U {j != i : v[j] > 1}). Exactness: all counts are
// nonneg integers; 0/1 entries are sums of tiny exact terms (exact in fp32
// in both this and the reference's matmuls); entries >= 2 can round but
// never below the >1 threshold => classification identical to reference. ----
__global__ __launch_bounds__(256) void k_walk(
        const unsigned* __restrict__ deg, const int* __restrict__ cols,
        float* __restrict__ rmap, int N) {
    __shared__ float v0[512], v1[512];
    __shared__ int red[4];
    int i = blockIdx.x, tid = threadIdx.x;
    for (int j = tid; j < N; j += 256) v0[j] = (j == i) ? 1.0f : 0.0f;
    __syncthreads();
    float* cur = v0; float* nxt = v1;
    for (int it = 0; it < 10; ++it) {
        for (int j = tid; j < N; j += 256) {
            float s = cur[j];
            unsigned d = deg[j];
            const int* cj = cols + (size_t)j * DEGCAP;
            for (unsigned k = 0; k < d; ++k) s += cur[cj[k]];
            nxt[j] = s;
        }
        __syncthreads();
        float* t = cur; cur = nxt; nxt = t;
    }
    int best = i;
    for (int j = tid; j < N; j += 256)
        if (j != i && cur[j] > 1.0f && j > best) best = j;
    for (int off = 32; off; off >>= 1) {
        int o = __shfl_down(best, off);
        if (o > best) best = o;
    }
    if ((tid & 63) == 0) red[tid >> 6] = best;
    __syncthreads();
    if (tid == 0) {
        for (int w = 1; w < 4; ++w) if (red[w] > best) best = red[w];
        rmap[i] = (float)(best + 1);
    }
}

// ---- binBfin: block b merges bucket b from all slabs + overflow lists via
// LDS atomicMax, writes output segment [b<<BSH,(b+1)<<BSH) through rmap.
// 1024 threads: 16 waves/CU to hide the scattered-run read latency. ----
__global__ __launch_bounds__(BFIN_THR) void k_binBfin(
        const unsigned* __restrict__ cnt, const u64* __restrict__ buf,
        const unsigned* __restrict__ ovfcnt, const u64* __restrict__ ovf,
        const float* __restrict__ rmap, float* __restrict__ out,
        int total, int NB1) {
    __shared__ unsigned bins[1 << BSH];  // 16 KB
    __shared__ unsigned lc[NBLKA];       // 2 KB
    __shared__ unsigned oc[NBLKA];       // 2 KB
    int b = blockIdx.x, tid = threadIdx.x;
    for (int i = tid; i < (1 << BSH); i += BFIN_THR) bins[i] = 0u;
    for (int s = tid; s < NBLKA; s += BFIN_THR) {
        lc[s] = cnt[(size_t)s * NBK + b];
        oc[s] = ovfcnt[s];
    }
    __syncthreads();
    for (int j = tid; j < NBLKA * CAPB; j += BFIN_THR) {
        int s = j >> 5, slot = j & (CAPB - 1);
        if (slot < (int)lc[s]) {
            u64 kv = buf[((size_t)s * NBK + b) * CAPB + slot];
            atomicMax(&bins[(unsigned)(kv >> 32)], (unsigned)kv);
        }
    }
    for (int j = tid; j < NBLKA * OVFC; j += BFIN_THR) {
        int s = j / OVFC, e = j % OVFC;
        if (e < (int)oc[s]) {
            u64 kv = ovf[(size_t)s * OVFC + e];
            unsigned key = (unsigned)(kv >> 32);
            if ((int)(key >> BSH) == b)
                atomicMax(&bins[key & BMSK], (unsigned)kv);
        }
    }
    __syncthreads();
    int base = b << BSH;
    for (int i = tid; i < (1 << BSH); i += BFIN_THR) {
        int g = base + i;
        if (g < total) {
            unsigned v = bins[i];
            out[g] = v ? rmap[NB1 - (int)(v & 0x1FFu)] : 0.0f;
        }
    }
}

// ---- Fallback path (ws too small): direct atomics + separate edges ----
__global__ __launch_bounds__(256) void k_scatter(
        const float* __restrict__ prob, const int* __restrict__ coords,
        unsigned* __restrict__ packed, int NE, int HW4, int NB1,
        const int* __restrict__ d_size1) {
    int i4 = blockIdx.x * blockDim.x + threadIdx.x;
    if (i4 * 4 >= NE) return;
    int size1 = *d_size1;
    float4 p = ((const float4*)prob)[i4];
    int4 x = ((const int4*)coords)[i4];
    int4 y = ((const int4*)(coords + NE))[i4];
    unsigned n = (unsigned)i4 / (unsigned)HW4;
    unsigned tie = (unsigned)(NB1 - (int)n);
    float pv[4] = {p.x, p.y, p.z, p.w};
    int   xv[4] = {x.x, x.y, x.z, x.w};
    int   yv[4] = {y.x, y.y, y.z, y.w};
#pragma unroll
    for (int e = 0; e < 4; ++e)
        if (pv[e] >= MASK_THR) {
            unsigned v = ((__float_as_uint(pv[e]) & 0x7FFFFFu) << 9) | tie;
            atomicMax(&packed[xv[e] * size1 + yv[e]], v);
        }
}

__global__ void k_edges(const float* __restrict__ adj, unsigned* __restrict__ deg,
                        int* __restrict__ cols, int N) {
    __shared__ unsigned lcnt;
    int r = blockIdx.x, tid = threadIdx.x;
    if (tid == 0) lcnt = 0u;
    __syncthreads();
    for (int c = tid; c < N; c += blockDim.x)
        if (adj[(size_t)r * N + c] != 0.0f) {
            unsigned pos = atomicAdd(&lcnt, 1u);
            if (pos < DEGCAP) cols[(size_t)r * DEGCAP + pos] = c;
        }
    __syncthreads();
    if (tid == 0) deg[r] = min(lcnt, (unsigned)DEGCAP);
}

__global__ void k_finalize(const unsigned* __restrict__ packed,
                           const float* __restrict__ rmap,
                           float* __restrict__ out, int total, int NB1) {
    int i4 = blockIdx.x * blockDim.x + threadIdx.x;
    if (i4 * 4 >= total) return;
    uint4 u = ((const uint4*)packed)[i4];
    unsigned v[4] = {u.x, u.y, u.z, u.w};
    float o[4];
#pragma unroll
    for (int e = 0; e < 4; ++e)
        o[e] = v[e] ? rmap[NB1 - (int)(v[e] & 0x1FFu)] : 0.0f;
    ((float4*)out)[i4] = make_float4(o[0], o[1], o[2], o[3]);
}

extern "C" void kernel_launch(void* const* d_in, const int* in_sizes, int n_in,
                              void* d_out, int out_size, void* d_ws, size_t ws_size,
                              hipStream_t stream) {
    const float* prob   = (const float*)d_in[0];
    const int*   coords = (const int*)d_in[1];
    const float* adj    = (const float*)d_in[2];
    const int*   dsz1   = (const int*)d_in[4];

    const int NE = in_sizes[0];            // 4718592
    const int NN = in_sizes[2];            // 512*512
    int N = (int)(sqrt((double)NN) + 0.5); // 512
    const int HW = NE / N;                 // 9216
    const int total = out_size;            // 1048576
    const int NB1 = N - 1;
    const int nbuck = (total + BMSK) >> BSH;   // 256

    char* ws = (char*)d_ws;
    const size_t slabB = (size_t)NBLKA * NBK * CAPB * 8;   // 33.55 MB
    const size_t cntB  = (size_t)NBLKA * NBK * 4;          // 512 KB
    const size_t ocB   = (size_t)NBLKA * 4;                // 2 KB
    const size_t ovfB  = (size_t)NBLKA * OVFC * 8;         // 256 KB
    const size_t colB  = (size_t)512 * DEGCAP * 4;         // 128 KB
    const size_t degB  = 512 * 4;
    const size_t rmapB = 512 * 4;
    const size_t needBin = slabB + cntB + ocB + ovfB + colB + degB + rmapB + 256;

    bool binOK = (nbuck <= NBK) && (N <= 512) && (N <= NBLKA) &&
                 (NE % 4 == 0) && (HW % 4 == 0) && (ws_size >= needBin);

    if (binOK) {
        size_t off = 0;
        u64* buf = (u64*)(ws + off); off += slabB;
        unsigned* cnt = (unsigned*)(ws + off); off += cntB;
        unsigned* ovfcnt = (unsigned*)(ws + off); off += ocB;
        u64* ovf = (u64*)(ws + off); off += ovfB;
        int* cols = (int*)(ws + off); off += colB;
        unsigned* deg = (unsigned*)(ws + off); off += degB;
        float* rmap = (float*)(ws + off);

        int NE4 = NE / 4;
        int i4PerBlk = (NE4 + NBLKA - 1) / NBLKA;
        k_binA<<<NBLKA, BLKA_THR, 0, stream>>>(
            prob, coords, adj, cnt, buf, ovfcnt, ovf, deg, cols,
            NE, HW / 4, NB1, dsz1, i4PerBlk, nbuck, N);

        k_walk<<<N, 256, 0, stream>>>(deg, cols, rmap, N);

        k_binBfin<<<nbuck, BFIN_THR, 0, stream>>>(cnt, buf, ovfcnt, ovf, rmap,
                                                  (float*)d_out, total, NB1);
    } else {
        unsigned* packed = (unsigned*)ws;
        size_t off = (size_t)total * 4;
        int* cols = (int*)(ws + off); off += colB;
        unsigned* deg = (unsigned*)(ws + off); off += degB;
        float* rmap = (float*)(ws + off);

        hipMemsetAsync(packed, 0, (size_t)total * 4, stream);
        k_scatter<<<(NE / 4 + 255) / 256, 256, 0, stream>>>(
            prob, coords, packed, NE, HW / 4, NB1, dsz1);
        k_edges<<<N, 256, 0, stream>>>(adj, deg, cols, N);
        k_walk<<<N, 256, 0, stream>>>(deg, cols, rmap, N);
        k_finalize<<<(total / 4 + 255) / 256, 256, 0, stream>>>(
            packed, rmap, (float*)d_out, total, NB1);
    }
}